// Round 5
// baseline (263.696 us; speedup 1.0000x reference)
//
#include <hip/hip_runtime.h>
#include <cstdint>

#define KK 16384
#define EE 256
#define M_USED 1792
#define NKC 16
#define LRELU_ALPHA 0.2f

typedef __bf16 bf16x8 __attribute__((ext_vector_type(8)));
typedef float f32x4 __attribute__((ext_vector_type(4)));

// shorts strides for packed fragment-tile layouts: tile = [16 rows][32 k] = 512 shorts
#define KH_N    512                 // total kh steps (16384/32)
#define OG_STR  (KH_N*512)          // 262144 shorts per o-group
#define MG_STR  (KH_N*512)          // 262144 shorts per m-group
#define MT_STR  (4*MG_STR)          // 1048576 shorts per m-tile (4 m-groups)

// ws layout: Wpack 8 MB | Hpack 64 MB | part 29.36 MB | Wh 1.84 MB
#define WP_BYTES (16u*OG_STR*2u)                 // 8 MB
#define HP_BYTES (32u*MT_STR*2u)                 // 64 MB

__device__ __forceinline__ unsigned short f2bf(float f){
  union { float f; unsigned u; } x; x.f = f;
  unsigned r = x.u + 0x7fffu + ((x.u >> 16) & 1u);
  return (unsigned short)(r >> 16);
}

// ---------- Kernel 1: W[16384][256] f32 -> Wpack[og][kh][16o x 32k] bf16 ----------
// block bk: k-rows [bk*128, bk*128+128), sequential read
__global__ __launch_bounds__(256) void k_pack_w(const float* __restrict__ W,
                                                unsigned short* __restrict__ Wp){
  __shared__ unsigned short Tw[256*136];   // [o][k_l], stride 136 (16B-aligned rows)
  const int tid = threadIdx.x;
  const int bk  = blockIdx.x;
  const int k0  = bk*128;
  // read 128 k-rows x 64 float4 sequentially
  #pragma unroll
  for (int it = 0; it < 32; ++it){
    int j   = tid + it*256;          // 0..8191
    int k_l = j >> 6;
    int o4  = j & 63;
    float4 v = *reinterpret_cast<const float4*>(W + (size_t)(k0 + k_l)*EE + o4*4);
    Tw[(o4*4+0)*136 + k_l] = f2bf(v.x);
    Tw[(o4*4+1)*136 + k_l] = f2bf(v.y);
    Tw[(o4*4+2)*136 + k_l] = f2bf(v.z);
    Tw[(o4*4+3)*136 + k_l] = f2bf(v.w);
  }
  __syncthreads();
  // write 64 tiles (16 og x 4 kh_l), one contiguous 1KB per wave
  const int wv = tid >> 6, lane = tid & 63, col = lane & 15, quad = lane >> 4;
  #pragma unroll
  for (int i = 0; i < 16; ++i){
    int tidx = wv*16 + i;
    int og = tidx >> 2, kh_l = tidx & 3;
    bf16x8 v = *reinterpret_cast<const bf16x8*>(&Tw[(og*16 + col)*136 + kh_l*32 + quad*8]);
    *reinterpret_cast<bf16x8*>(Wp + (size_t)og*OG_STR + (size_t)(bk*4 + kh_l)*512
                               + col*32 + quad*8) = v;
  }
}

// ---------- Kernel 2: h[n][c][t][v] f32 -> Hpack[mt][mg][kh][16m x 32k] bf16 ----------
// block (mt, cc): n-range mt*8..+8, c-range cc*8..+8; reads 8x14KB contiguous segments
__global__ __launch_bounds__(256) void k_pack_h(const float* __restrict__ h,
                                                unsigned short* __restrict__ Hp){
  __shared__ unsigned short Tm[64*520];    // [m][k_l], stride 520 (16B-aligned rows)
  const int tid = threadIdx.x;
  const int mt  = blockIdx.x;
  const int cc  = blockIdx.y;
  const int n0  = mt*8;
  const int c0  = cc*8;
  // zero pad rows m=56..63
  for (int idx = tid; idx < 8*520; idx += 256) Tm[56*520 + idx] = 0;
  // read 8n x 8c x 112 float4 = 7168 float4, sequential per (n,c) row
  #pragma unroll
  for (int it = 0; it < 28; ++it){
    int j  = tid + it*256;           // 0..7167
    int nn = j / 896;
    int r  = j - nn*896;
    int ci = r / 112;
    int f  = r - ci*112;
    float4 v = *reinterpret_cast<const float4*>(
        h + (size_t)(n0+nn)*114688 + (size_t)(c0+ci)*448 + f*4);
    float vv[4] = {v.x, v.y, v.z, v.w};
    #pragma unroll
    for (int e = 0; e < 4; ++e){
      int rr = f*4 + e;
      int t_ = rr / 7;
      int v_ = rr - t_*7;
      Tm[(nn*7 + v_)*520 + ci*64 + t_] = f2bf(vv[e]);
    }
  }
  __syncthreads();
  // write 64 tiles (4 mg x 16 kh_l), one contiguous 1KB per wave
  const int wv = tid >> 6, lane = tid & 63, col = lane & 15, quad = lane >> 4;
  #pragma unroll
  for (int i = 0; i < 16; ++i){
    int tidx = wv*16 + i;
    int mg = tidx >> 4, kh_l = tidx & 15;
    bf16x8 v = *reinterpret_cast<const bf16x8*>(&Tm[(mg*16 + col)*520 + kh_l*32 + quad*8]);
    *reinterpret_cast<bf16x8*>(Hp + (size_t)mt*MT_STR + (size_t)mg*MG_STR
                               + (size_t)(cc*16 + kh_l)*512 + col*32 + quad*8) = v;
  }
}

// ---------- Kernel 3: register GEMM, no LDS, no barriers ----------
// grid (32 mt, 16 kc), 256 thr = 4 waves; wave w: o-groups w*4..w*4+4 x all 4 mg
__global__ __launch_bounds__(256, 2) void k_gemm(const unsigned short* __restrict__ Wp,
                                                 const unsigned short* __restrict__ Hp,
                                                 float* __restrict__ part){
  const int tid  = threadIdx.x;
  const int mt   = blockIdx.x;
  const int kc   = blockIdx.y;
  const int w    = tid >> 6;
  const int lane = tid & 63;
  const int col  = lane & 15;
  const int quad = lane >> 4;
  const int lofs = col*32 + quad*8;

  const unsigned short* A0 = Wp + (size_t)(w*4)*OG_STR + (size_t)(kc*32)*512 + lofs;
  const unsigned short* B0 = Hp + (size_t)mt*MT_STR   + (size_t)(kc*32)*512 + lofs;

  f32x4 acc[4][4];
  #pragma unroll
  for (int a_ = 0; a_ < 4; ++a_)
    #pragma unroll
    for (int b_ = 0; b_ < 4; ++b_)
      acc[a_][b_] = (f32x4){0.f, 0.f, 0.f, 0.f};

  bf16x8 a0[4], b0[4], a1[4], b1[4];
  #pragma unroll
  for (int i = 0; i < 4; ++i){
    a0[i] = *reinterpret_cast<const bf16x8*>(A0 + (size_t)i*OG_STR);
    b0[i] = *reinterpret_cast<const bf16x8*>(B0 + (size_t)i*MG_STR);
  }

  for (int s = 0; s < 32; s += 2){
    // prefetch kh s+1 (always in range: s+1 <= 31)
    #pragma unroll
    for (int i = 0; i < 4; ++i){
      a1[i] = *reinterpret_cast<const bf16x8*>(A0 + (size_t)i*OG_STR + (s+1)*512);
      b1[i] = *reinterpret_cast<const bf16x8*>(B0 + (size_t)i*MG_STR + (s+1)*512);
    }
    #pragma unroll
    for (int oi = 0; oi < 4; ++oi)
      #pragma unroll
      for (int mi = 0; mi < 4; ++mi)
        acc[oi][mi] = __builtin_amdgcn_mfma_f32_16x16x32_bf16(a0[oi], b0[mi], acc[oi][mi], 0, 0, 0);
    // prefetch kh s+2 (clamped at tail to avoid OOB; values unused then)
    const int sn = (s+2 < 32) ? s+2 : 30;
    #pragma unroll
    for (int i = 0; i < 4; ++i){
      a0[i] = *reinterpret_cast<const bf16x8*>(A0 + (size_t)i*OG_STR + sn*512);
      b0[i] = *reinterpret_cast<const bf16x8*>(B0 + (size_t)i*MG_STR + sn*512);
    }
    #pragma unroll
    for (int oi = 0; oi < 4; ++oi)
      #pragma unroll
      for (int mi = 0; mi < 4; ++mi)
        acc[oi][mi] = __builtin_amdgcn_mfma_f32_16x16x32_bf16(a1[oi], b1[mi], acc[oi][mi], 0, 0, 0);
  }

  // partials: part[kc][o][mt*56 + ml], ml < 56
  #pragma unroll
  for (int oi = 0; oi < 4; ++oi){
    #pragma unroll
    for (int r = 0; r < 4; ++r){
      int o = (w*4 + oi)*16 + quad*4 + r;
      size_t rowbase = ((size_t)(kc*256 + o))*M_USED + mt*56;
      #pragma unroll
      for (int mi = 0; mi < 4; ++mi){
        int ml = mi*16 + col;
        if (ml < 56) part[rowbase + ml] = acc[oi][mi][r];
      }
    }
  }
}

// ---------- Kernel 4: reduce partials over kc ----------
__global__ __launch_bounds__(256) void k_reduce(const float* __restrict__ part,
                                                float* __restrict__ Wh){
  const int m = blockIdx.x*256 + threadIdx.x;
  const int o = blockIdx.y;
  float s = 0.f;
  #pragma unroll
  for (int k = 0; k < NKC; ++k)
    s += part[((size_t)(k*256 + o))*M_USED + m];
  Wh[(size_t)o*M_USED + m] = s;
}

// ---------- Kernel 5: attention + elu ----------
__global__ __launch_bounds__(256) void k_attn(const float* __restrict__ Wh,
                                              const float* __restrict__ a,
                                              const float* __restrict__ Bp,
                                              float* __restrict__ out){
  const int n    = blockIdx.x;
  const int tid  = threadIdx.x;
  const int lane = tid & 63;
  const int wv   = tid >> 6;

  __shared__ float adjn[49];
  __shared__ float red1[4][7], red2[4][7];
  __shared__ float s1s[7], s2s[7];
  __shared__ float att0[49], att[49];

  if (tid == 0){
    float adj[49];
    float mn = 1e30f, mx = -1e30f;
    for (int i = 0; i < 7; ++i)
      for (int j = 0; j < 7; ++j){
        float x = Bp[i*7+j] + 1e-6f + (i == j ? 1.f : 0.f);
        adj[i*7+j] = x;
        mn = fminf(mn, x); mx = fmaxf(mx, x);
      }
    float inv = 1.f / (mx - mn);
    for (int i = 0; i < 49; ++i) adj[i] = (adj[i] - mn) * inv;
    float d12[7];
    for (int i = 0; i < 7; ++i){
      float s = 0.f;
      for (int j = 0; j < 7; ++j) s += adj[i*7+j];
      d12[i] = 1.f / sqrtf(s);
    }
    for (int i = 0; i < 7; ++i)
      for (int j = 0; j < 7; ++j)
        adjn[i*7+j] = d12[i] * adj[i*7+j] * d12[j];
  }

  float wh[7];
  #pragma unroll
  for (int v = 0; v < 7; ++v)
    wh[v] = Wh[(size_t)tid*M_USED + n*7 + v];

  const float a1 = a[tid];
  const float a2 = a[256 + tid];

  #pragma unroll
  for (int v = 0; v < 7; ++v){
    float x1 = wh[v]*a1;
    float x2 = wh[v]*a2;
    #pragma unroll
    for (int off = 32; off > 0; off >>= 1){
      x1 += __shfl_down(x1, off);
      x2 += __shfl_down(x2, off);
    }
    if (lane == 0){ red1[wv][v] = x1; red2[wv][v] = x2; }
  }
  __syncthreads();
  if (tid < 7){
    s1s[tid] = red1[0][tid]+red1[1][tid]+red1[2][tid]+red1[3][tid];
    s2s[tid] = red2[0][tid]+red2[1][tid]+red2[2][tid]+red2[3][tid];
  }
  __syncthreads();
  if (tid < 7){
    const int v = tid;
    float e[7]; float mx = -1e30f;
    #pragma unroll
    for (int u = 0; u < 7; ++u){
      float t = s1s[v] + s2s[u];
      t = t > 0.f ? t : LRELU_ALPHA*t;
      e[u] = t; mx = fmaxf(mx, t);
    }
    float sum = 0.f;
    #pragma unroll
    for (int u = 0; u < 7; ++u){ e[u] = expf(e[u]-mx); sum += e[u]; }
    float inv = 1.f/sum;
    #pragma unroll
    for (int u = 0; u < 7; ++u) att0[v*7+u] = e[u]*inv;
  }
  __syncthreads();
  if (tid < 7){
    const int v = tid;
    #pragma unroll
    for (int u = 0; u < 7; ++u){
      float s = 0.f;
      #pragma unroll
      for (int w7 = 0; w7 < 7; ++w7) s += adjn[v*7+w7]*att0[w7*7+u];
      att[v*7+u] = s;
    }
  }
  __syncthreads();
  #pragma unroll
  for (int v = 0; v < 7; ++v){
    float hp = 0.f;
    #pragma unroll
    for (int u = 0; u < 7; ++u) hp += att[v*7+u]*wh[u];
    float o = hp > 0.f ? hp : expm1f(hp);
    out[(size_t)(n*7+v)*256 + tid] = o;
  }
}

extern "C" void kernel_launch(void* const* d_in, const int* in_sizes, int n_in,
                              void* d_out, int out_size, void* d_ws, size_t ws_size,
                              hipStream_t stream){
  const float* h  = (const float*)d_in[0];
  const float* W  = (const float*)d_in[1];
  const float* a  = (const float*)d_in[2];
  const float* Bp = (const float*)d_in[3];
  float* out = (float*)d_out;
  char* ws = (char*)d_ws;

  unsigned short* Wp   = (unsigned short*)ws;
  unsigned short* Hp   = (unsigned short*)(ws + WP_BYTES);
  float*          part = (float*)(ws + WP_BYTES + HP_BYTES);
  float*          Wh   = part + (size_t)NKC * 256 * M_USED;

  k_pack_w<<<128, 256, 0, stream>>>(W, Wp);
  k_pack_h<<<dim3(32, 32), 256, 0, stream>>>(h, Hp);
  k_gemm<<<dim3(32, NKC), 256, 0, stream>>>(Wp, Hp, part);
  k_reduce<<<dim3(7, 256), 256, 0, stream>>>(part, Wh);
  k_attn<<<256, 256, 0, stream>>>(Wh, a, Bp, out);
}